// Round 4
// baseline (83.922 us; speedup 1.0000x reference)
//
#include <hip/hip_runtime.h>
#include <math.h>

#define N_WAVES 128
#define BLOCK 256
#define PPT 2   // points per thread

// out[n] = sum_w c0*sin(2pi*f*(x0*cos r + x1*sin r)) + c1*cos(...)
//        = sum_w R_w * sin(2pi*(a_w*x0 + b_w*x1) + phi_w)
// a = f*cos r, b = f*sin r, R = hypot(c0,c1), phi = atan2(c1,c0).
// v_sin_f32 computes sin(2pi*x) -> phase in revolutions, reduce w/ v_fract.
//
// R4: (1) setup fused back into the kernel with cheap HW sin/cos
//     (r in [0,pi) -> r/2pi in [0,0.5), in-range for v_sin/v_cos, no libm
//     sincos); only atan2f stays libm (once per block, 128 threads).
//     No setup kernel, no d_ws use -> one kernel, fewer graph nodes.
// (2) DECOMPOSITION PROBE: kernel launched TWICE (idempotent, same output).
//     dur_us = overhead + 2*T tells us T vs the ~41us harness poison floor.

__global__ __launch_bounds__(BLOCK) void periodic2d_kernel(
    const float* __restrict__ x,      // [N,2]
    const float* __restrict__ freqs,  // [W]
    const float* __restrict__ rots,   // [W]
    const float* __restrict__ coeffs, // [W,2]
    float* __restrict__ out,          // [N]
    int n)
{
    __shared__ float4 wp[N_WAVES];  // {a, b, phi_rev, amp}
    const int tid = threadIdx.x;
    const float inv2pi = 0.15915494309189535f;

    if (tid < N_WAVES) {
        float f  = freqs[tid];
        float r  = rots[tid];
        float c0 = coeffs[2 * tid];
        float c1 = coeffs[2 * tid + 1];
        float rr = r * inv2pi;                    // [0, 0.5) -> in range
        float sr = __builtin_amdgcn_sinf(rr);     // HW v_sin_f32
        float cr = __builtin_amdgcn_cosf(rr);     // HW v_cos_f32
        float amp = sqrtf(c0 * c0 + c1 * c1);
        float phi = atan2f(c1, c0) * inv2pi;      // rad -> revs
        wp[tid] = make_float4(f * cr, f * sr, phi, amp);
    }
    __syncthreads();

    const int ia = blockIdx.x * (BLOCK * PPT) + tid;
    const int ib = ia + BLOCK;

    const float2* __restrict__ X2 = (const float2*)x;
    float x0a = 0.f, x1a = 0.f, x0b = 0.f, x1b = 0.f;
    if (ia < n) { float2 v = X2[ia]; x0a = v.x; x1a = v.y; }
    if (ib < n) { float2 v = X2[ib]; x0b = v.x; x1b = v.y; }

    float acca = 0.f, accb = 0.f;
#pragma unroll 8
    for (int w = 0; w < N_WAVES; ++w) {
        float4 p = wp[w];
        float pa = __builtin_fmaf(p.x, x0a, __builtin_fmaf(p.y, x1a, p.z));
        float ta = __builtin_amdgcn_fractf(pa);
        float sa = __builtin_amdgcn_sinf(ta);
        acca = __builtin_fmaf(p.w, sa, acca);

        float pb = __builtin_fmaf(p.x, x0b, __builtin_fmaf(p.y, x1b, p.z));
        float tb = __builtin_amdgcn_fractf(pb);
        float sb = __builtin_amdgcn_sinf(tb);
        accb = __builtin_fmaf(p.w, sb, accb);
    }

    if (ia < n) out[ia] = acca;
    if (ib < n) out[ib] = accb;
}

extern "C" void kernel_launch(void* const* d_in, const int* in_sizes, int n_in,
                              void* d_out, int out_size, void* d_ws, size_t ws_size,
                              hipStream_t stream) {
    const float* x      = (const float*)d_in[0];
    const float* freqs  = (const float*)d_in[1];
    const float* rots   = (const float*)d_in[2];
    const float* coeffs = (const float*)d_in[3];
    float* out = (float*)d_out;

    const int n = out_size;  // 500,000 points
    const int grid = (n + BLOCK * PPT - 1) / (BLOCK * PPT);  // 977 blocks

    // PROBE: two identical launches. Idempotent -> output unchanged.
    // dur_us(R4) - dur_us(R3) ~= T_kernel.
    periodic2d_kernel<<<grid, BLOCK, 0, stream>>>(x, freqs, rots, coeffs, out, n);
    periodic2d_kernel<<<grid, BLOCK, 0, stream>>>(x, freqs, rots, coeffs, out, n);
}

// Round 5
// 73.266 us; speedup vs baseline: 1.1454x; 1.1454x over previous
//
#include <hip/hip_runtime.h>
#include <math.h>

#define N_WAVES 128
#define BLOCK 256
#define PPT 1   // 1 point/thread -> 7.6 waves/SIMD for trans-pipe overlap

// out[n] = sum_w c0*sin(2pi*f*(x0*cos r + x1*sin r)) + c1*cos(...)
//        = sum_w R_w * sin(2pi*(a_w*x0 + b_w*x1) + phi_w)
// v_sin_f32 computes sin(2pi*x) -> phase in revolutions, v_fract reduce.
// Measured decomposition (R3 vs R4 double-launch probe): T_main ~= 11.2 us,
// harness fixed overhead ~= 61 us. Model: 27.5 cyc per wave-term =
// 4 full-rate VALU (8 cyc) + v_sin (~16 cyc) issue-serialized.
// R5 tests whether high wave-occupancy lets other waves' VALU overlap the
// trans pipe (floor -> 16 cyc/term ~ 6.5 us).

__global__ void setup_kernel(const float* __restrict__ freqs,
                             const float* __restrict__ rots,
                             const float* __restrict__ coeffs,
                             float4* __restrict__ wp_out) {
    int w = threadIdx.x;
    if (w < N_WAVES) {
        float f  = freqs[w];
        float r  = rots[w];
        float c0 = coeffs[2 * w];
        float c1 = coeffs[2 * w + 1];
        float sr, cr;
        sincosf(r, &sr, &cr);              // setup-only: accurate libm
        float amp = sqrtf(c0 * c0 + c1 * c1);
        float phi = atan2f(c1, c0) * 0.15915494309189535f;  // rad -> revs
        wp_out[w] = make_float4(f * cr, f * sr, phi, amp);
    }
}

__global__ __launch_bounds__(BLOCK, 8) void periodic2d_kernel(
    const float* __restrict__ x,      // [N,2]
    const float4* __restrict__ wp,    // [W] {a,b,phi_rev,amp} uniform reads
    float* __restrict__ out,          // [N]
    int n)
{
    const int i = blockIdx.x * BLOCK + threadIdx.x;

    float x0 = 0.f, x1 = 0.f;
    if (i < n) {
        float2 v = ((const float2*)x)[i];
        x0 = v.x; x1 = v.y;
    }

    float acc = 0.f;
#pragma unroll 16
    for (int w = 0; w < N_WAVES; ++w) {
        const float4 p = wp[w];   // uniform -> s_load_dwordx4, scalar pipe
        float ph = __builtin_fmaf(p.x, x0, __builtin_fmaf(p.y, x1, p.z));
        float t  = __builtin_amdgcn_fractf(ph);
        float s  = __builtin_amdgcn_sinf(t);
        acc = __builtin_fmaf(p.w, s, acc);
    }

    if (i < n) out[i] = acc;
}

extern "C" void kernel_launch(void* const* d_in, const int* in_sizes, int n_in,
                              void* d_out, int out_size, void* d_ws, size_t ws_size,
                              hipStream_t stream) {
    const float* x      = (const float*)d_in[0];
    const float* freqs  = (const float*)d_in[1];
    const float* rots   = (const float*)d_in[2];
    const float* coeffs = (const float*)d_in[3];
    float* out = (float*)d_out;
    float4* wp = (float4*)d_ws;   // 2 KB scratch

    const int n = out_size;  // 500,000
    setup_kernel<<<1, N_WAVES, 0, stream>>>(freqs, rots, coeffs, wp);
    const int grid = (n + BLOCK - 1) / BLOCK;   // 1954 blocks
    periodic2d_kernel<<<grid, BLOCK, 0, stream>>>(x, wp, out, n);
}

// Round 6
// 73.072 us; speedup vs baseline: 1.1485x; 1.0027x over previous
//
#include <hip/hip_runtime.h>
#include <math.h>

#define N_WAVES 128
#define BLOCK 256

// out[n] = sum_w c0*sin(2pi*f*(x0*cos r + x1*sin r)) + c1*cos(...)
//        = sum_w R_w * sin(2pi*(a_w*x0 + b_w*x1) + phi_w)
//
// R6: replace HW v_sin_f32 (~16-21 cyc/wave, issue-serialized, no cross-wave
// overlap per R5 experiment) with a degree-7 odd minimax polynomial for
// sin(2pi*u), u in [-0.5,0.5) — pure full-rate FMA pipe, 10 ops = ~20 cyc/term
// vs ~29 measured. Max poly err ~3e-4 -> accumulated ~0.02 over 128 waves,
// fine vs 0.55 threshold.
//
// Identities folded into setup:
//   phi' = phi_rev + 0.5           -> u = fract(ph') - 0.5, sin(2pi*ph)=sin(2pi*u)
//   R'   = 2*hypot(c0,c1)          -> absorbs v=2u substitution
// sin(pi*v) ~= v*(a + b v^2 + c v^4 + d v^6), v in [-1,1]:
//   a=3.138982 b=-5.133625 c=2.428288 d=-0.433645  (err ~3e-4)
// in u (v=2u), leading 2 folded into R':
//   C1=a, C3=4b=-20.5345, C5=16c=38.852608, C7=64d=-27.75328

__global__ void setup_kernel(const float* __restrict__ freqs,
                             const float* __restrict__ rots,
                             const float* __restrict__ coeffs,
                             float4* __restrict__ wp_out) {
    int w = threadIdx.x;
    if (w < N_WAVES) {
        float f  = freqs[w];
        float r  = rots[w];
        float c0 = coeffs[2 * w];
        float c1 = coeffs[2 * w + 1];
        float sr, cr;
        sincosf(r, &sr, &cr);              // setup-only: accurate libm
        float amp2 = 2.0f * sqrtf(c0 * c0 + c1 * c1);
        float phi  = atan2f(c1, c0) * 0.15915494309189535f + 0.5f;
        wp_out[w] = make_float4(f * cr, f * sr, phi, amp2);
    }
}

__global__ __launch_bounds__(BLOCK) void periodic2d_kernel(
    const float* __restrict__ x,      // [N,2]
    const float4* __restrict__ wp,    // [W] {a,b,phi'+0.5,2R} uniform reads
    float* __restrict__ out,          // [N]
    int n)
{
    const float C1 = 3.138982f;
    const float C3 = -20.534500f;
    const float C5 = 38.852608f;
    const float C7 = -27.753280f;

    const int i = blockIdx.x * BLOCK + threadIdx.x;

    float x0 = 0.f, x1 = 0.f;
    if (i < n) {
        float2 v = ((const float2*)x)[i];
        x0 = v.x; x1 = v.y;
    }

    float acc = 0.f;
#pragma unroll 8
    for (int w = 0; w < N_WAVES; ++w) {
        const float4 p = wp[w];   // uniform -> s_load_dwordx4, scalar pipe
        float ph = __builtin_fmaf(p.x, x0, __builtin_fmaf(p.y, x1, p.z));
        float u  = __builtin_amdgcn_fractf(ph) - 0.5f;
        float u2 = u * u;
        float pl = __builtin_fmaf(u2, C7, C5);
        pl       = __builtin_fmaf(u2, pl, C3);
        pl       = __builtin_fmaf(u2, pl, C1);
        float ru = p.w * u;               // off the Horner critical path
        acc      = __builtin_fmaf(ru, pl, acc);
    }

    if (i < n) out[i] = acc;
}

extern "C" void kernel_launch(void* const* d_in, const int* in_sizes, int n_in,
                              void* d_out, int out_size, void* d_ws, size_t ws_size,
                              hipStream_t stream) {
    const float* x      = (const float*)d_in[0];
    const float* freqs  = (const float*)d_in[1];
    const float* rots   = (const float*)d_in[2];
    const float* coeffs = (const float*)d_in[3];
    float* out = (float*)d_out;
    float4* wp = (float4*)d_ws;   // 2 KB scratch

    const int n = out_size;  // 500,000
    setup_kernel<<<1, N_WAVES, 0, stream>>>(freqs, rots, coeffs, wp);
    const int grid = (n + BLOCK - 1) / BLOCK;   // 1954 blocks
    periodic2d_kernel<<<grid, BLOCK, 0, stream>>>(x, wp, out, n);
}